// Round 3
// baseline (331.546 us; speedup 1.0000x reference)
//
#include <hip/hip_runtime.h>

#define NEG_INF (-__builtin_inff())
#define SC_L2E 0.180336880111120f  // 0.125 * log2(e)

typedef _Float16 half8v __attribute__((ext_vector_type(8)));
typedef _Float16 half4v __attribute__((ext_vector_type(4)));
typedef _Float16 half2v __attribute__((ext_vector_type(2)));
typedef float f32x4 __attribute__((ext_vector_type(4)));
typedef float f32x16 __attribute__((ext_vector_type(16)));

#if __has_builtin(__builtin_amdgcn_exp2f)
#define EXP2(x) __builtin_amdgcn_exp2f(x)
#else
#define EXP2(x) exp2f(x)
#endif

#if __has_builtin(__builtin_amdgcn_cvt_pkrtz)
#define CVTPK(a, b) __builtin_amdgcn_cvt_pkrtz((a), (b))
#else
static __device__ __forceinline__ half2v cvtpk_fb(float a, float b) {
  half2v h; h[0] = (_Float16)a; h[1] = (_Float16)b; return h;
}
#define CVTPK cvtpk_fb
#endif

__device__ __forceinline__ void gload_lds16(const void* g, void* l) {
  __builtin_amdgcn_global_load_lds(
      (const __attribute__((address_space(1))) void*)g,
      (__attribute__((address_space(3))) void*)l, 16, 0, 0);
}

// ---------------------------------------------------------------------------
// Mask dtype detection: int32 0/1 has zero bytes at idx%4!=0; uint8 bool does
// not. All-zero mask degenerates identically either way.
// ---------------------------------------------------------------------------
__global__ __launch_bounds__(256) void detect_mask_kernel(
    const unsigned char* __restrict__ m, int* __restrict__ flag) {
  __shared__ int sany;
  if (threadIdx.x == 0) sany = 0;
  __syncthreads();
  int any = 0;
  for (int i = threadIdx.x; i < 8 * 512; i += 256)
    if ((i & 3) != 0 && m[i] != 0) any = 1;
  if (any) sany = 1;
  __syncthreads();
  if (threadIdx.x == 0) *flag = sany;  // 1 => uint8, 0 => int32
}

// ---------------------------------------------------------------------------
// Fused LayerNorm + fp16 cast. One block per row, D=1024.
// ---------------------------------------------------------------------------
__global__ __launch_bounds__(256) void ln_cast_kernel(
    const float* __restrict__ X, const float* __restrict__ ga,
    const float* __restrict__ be, _Float16* __restrict__ Y) {
  const int row = blockIdx.x;
  const int t = threadIdx.x;
  const float4 x = ((const float4*)(X + (size_t)row * 1024))[t];
  float s  = x.x + x.y + x.z + x.w;
  float ss = x.x * x.x + x.y * x.y + x.z * x.z + x.w * x.w;
#pragma unroll
  for (int off = 32; off > 0; off >>= 1) {
    s  += __shfl_down(s, off);
    ss += __shfl_down(ss, off);
  }
  __shared__ float red[8];
  __shared__ float smu, srs;
  if ((t & 63) == 0) { red[(t >> 6) * 2] = s; red[(t >> 6) * 2 + 1] = ss; }
  __syncthreads();
  if (t == 0) {
    const float S  = red[0] + red[2] + red[4] + red[6];
    const float SS = red[1] + red[3] + red[5] + red[7];
    const float mm = S * (1.f / 1024.f);
    const float vv = SS * (1.f / 1024.f) - mm * mm;
    smu = mm; srs = rsqrtf(vv + 1e-5f);
  }
  __syncthreads();
  const float mu = smu, rs = srs;
  const float4 g  = ((const float4*)ga)[t];
  const float4 bb = ((const float4*)be)[t];
  half4v y;
  y[0] = (_Float16)((x.x - mu) * rs * g.x + bb.x);
  y[1] = (_Float16)((x.y - mu) * rs * g.y + bb.y);
  y[2] = (_Float16)((x.z - mu) * rs * g.z + bb.z);
  y[3] = (_Float16)((x.w - mu) * rs * g.w + bb.w);
  ((half4v*)(Y + (size_t)row * 1024))[t] = y;
}

// ---------------------------------------------------------------------------
// fp32 -> fp16 cast, 8 elements/thread.
// ---------------------------------------------------------------------------
__global__ __launch_bounds__(256) void cast_f2h_kernel(
    const float* __restrict__ X, _Float16* __restrict__ Y, int n8) {
  const int i = blockIdx.x * 256 + threadIdx.x;
  if (i >= n8) return;
  const float4 a  = ((const float4*)X)[i * 2];
  const float4 b2 = ((const float4*)X)[i * 2 + 1];
  half8v y;
  y[0] = (_Float16)a.x;  y[1] = (_Float16)a.y;
  y[2] = (_Float16)a.z;  y[3] = (_Float16)a.w;
  y[4] = (_Float16)b2.x; y[5] = (_Float16)b2.y;
  y[6] = (_Float16)b2.z; y[7] = (_Float16)b2.w;
  ((half8v*)Y)[i] = y;
}

// ---------------------------------------------------------------------------
// Y = A @ W^T, fp16 inputs, MFMA 16x16x32_f16, K = 1024.
// 128x128 tile, BK=32, 256 threads (4 waves, each 64x64 output).
// EPI 0: fp16 out.  EPI 1: fp32 out + resid + bias.  EPI 2: fp16 transposed
// out (V^T layout: Y[(token>>9)*1024 + col][512] at n = token&511).
// ---------------------------------------------------------------------------
template <int EPI>
__global__ __launch_bounds__(256) void hgemm_nt(
    const _Float16* __restrict__ A, const _Float16* __restrict__ W,
    void* __restrict__ Yv, const float* __restrict__ bias,
    const float* __restrict__ resid) {
  __shared__ _Float16 As[4096];  // [128][32]
  __shared__ _Float16 Bs[4096];
  const int tid = threadIdx.x;
  const int bm = blockIdx.x, bn = blockIdx.y;
  const int wid = tid >> 6, lane = tid & 63;
  const int wr = wid >> 1, wc = wid & 1;
  const int l15 = lane & 15, lg = lane >> 4;

  f32x4 acc[4][4] = {};

  const int c0 = tid, c1 = tid + 256;
  const _Float16* Ag0 = A + (size_t)(bm * 128 + (c0 >> 2)) * 1024 + (c0 & 3) * 8;
  const _Float16* Ag1 = A + (size_t)(bm * 128 + (c1 >> 2)) * 1024 + (c1 & 3) * 8;
  const _Float16* Bg0 = W + (size_t)(bn * 128 + (c0 >> 2)) * 1024 + (c0 & 3) * 8;
  const _Float16* Bg1 = W + (size_t)(bn * 128 + (c1 >> 2)) * 1024 + (c1 & 3) * 8;
  _Float16* Asw0 = &As[wid * 512];
  _Float16* Asw1 = &As[wid * 512 + 2048];
  _Float16* Bsw0 = &Bs[wid * 512];
  _Float16* Bsw1 = &Bs[wid * 512 + 2048];

  for (int kt = 0; kt < 1024; kt += 32) {
    __syncthreads();
    gload_lds16(Ag0 + kt, Asw0);
    gload_lds16(Ag1 + kt, Asw1);
    gload_lds16(Bg0 + kt, Bsw0);
    gload_lds16(Bg1 + kt, Bsw1);
    __syncthreads();
    half8v a[4], b[4];
#pragma unroll
    for (int m = 0; m < 4; m++)
      a[m] = *(const half8v*)&As[(wr * 64 + m * 16 + l15) * 32 + lg * 8];
#pragma unroll
    for (int n = 0; n < 4; n++)
      b[n] = *(const half8v*)&Bs[(wc * 64 + n * 16 + l15) * 32 + lg * 8];
#pragma unroll
    for (int m = 0; m < 4; m++)
#pragma unroll
      for (int n = 0; n < 4; n++)
        acc[m][n] = __builtin_amdgcn_mfma_f32_16x16x32_f16(a[m], b[n], acc[m][n], 0, 0, 0);
  }

  if (EPI == 0) {
    _Float16* Y = (_Float16*)Yv;
#pragma unroll
    for (int m = 0; m < 4; m++) {
      const int gr0 = bm * 128 + wr * 64 + m * 16 + lg * 4;
#pragma unroll
      for (int n = 0; n < 4; n++) {
        const int gc = bn * 128 + wc * 64 + n * 16 + l15;
#pragma unroll
        for (int r = 0; r < 4; r++)
          Y[(size_t)(gr0 + r) * 1024 + gc] = (_Float16)acc[m][n][r];
      }
    }
  } else if (EPI == 1) {
    float* Y = (float*)Yv;
#pragma unroll
    for (int m = 0; m < 4; m++) {
      const int gr0 = bm * 128 + wr * 64 + m * 16 + lg * 4;
#pragma unroll
      for (int n = 0; n < 4; n++) {
        const int gc = bn * 128 + wc * 64 + n * 16 + l15;
        const float bv = bias[gc];
#pragma unroll
        for (int r = 0; r < 4; r++)
          Y[(size_t)(gr0 + r) * 1024 + gc] =
              acc[m][n][r] + bv + resid[(size_t)(gr0 + r) * 1024 + gc];
      }
    }
  } else {  // EPI == 2: transposed write for V^T
    _Float16* Y = (_Float16*)Yv;
#pragma unroll
    for (int m = 0; m < 4; m++) {
      const int gr0 = bm * 128 + wr * 64 + m * 16 + lg * 4;
#pragma unroll
      for (int n = 0; n < 4; n++) {
        const int gc = bn * 128 + wc * 64 + n * 16 + l15;
#pragma unroll
        for (int r = 0; r < 4; r++) {
          const int tokenv = gr0 + r;
          Y[(size_t)((tokenv >> 9) * 1024 + gc) * 512 + (tokenv & 511)] =
              (_Float16)acc[m][n][r];
        }
      }
    }
  }
}

// ---------------------------------------------------------------------------
// MFMA flash attention v3 (swapped operands, 32x32x16, no K/V LDS staging).
// Block = (b, head, 128 q); 4 independent waves x 32 q-rows; 16 kv-tiles of 32.
// S^T = mfma(K, Q): lane col (lane&31) = q-row -> softmax is lane-local
// (one shfl_xor(32) per reduce). P packed to fp16 in-reg (cvt_pkrtz) and
// redistributed with 8 shuffles into PV B-frags. O^T = mfma(V^T, P) with V^T
// frags read straight from global vT (L2-resident). Epilogue transposes O^T
// through swizzled per-wave LDS for coalesced fp16 stores.
// ---------------------------------------------------------------------------
__global__ __launch_bounds__(256) void attn_v3(
    const _Float16* __restrict__ q, const _Float16* __restrict__ kk,
    const _Float16* __restrict__ vT, const void* __restrict__ maskp,
    const int* __restrict__ flag, _Float16* __restrict__ ctx) {
  __shared__ float Msk[512];
  __shared__ _Float16 Ot[4][2048];

  const int bid = blockIdx.x;
  const int qt = bid & 15, hh = (bid >> 4) & 15, b = bid >> 8;
  const int tid = threadIdx.x;
  const int wid = tid >> 6, lane = tid & 63;
  const int l31 = lane & 31;
  const int hi  = lane >> 5;

  {
    const bool mu8 = (*flag != 0);
    const unsigned char* m8 = (const unsigned char*)maskp;
    const int* m32 = (const int*)maskp;
    for (int i = tid; i < 512; i += 256) {
      const bool mv = mu8 ? (m8[b * 512 + i] != 0) : (m32[b * 512 + i] != 0);
      Msk[i] = mv ? 0.f : NEG_INF;
    }
  }
  __syncthreads();

  const int tok0 = b * 2048 + qt * 128 + wid * 32;
  half8v bq[4];
#pragma unroll
  for (int kg = 0; kg < 4; kg++)
    bq[kg] = *(const half8v*)(q + (size_t)(tok0 + l31) * 1024 + hh * 64 + kg * 16 + hi * 8);

  float m_s = NEG_INF, l_s = 0.f;
  f32x16 ot0 = {}, ot1 = {};

  const _Float16* kb = kk + (size_t)b * 512 * 1024 + hh * 64;
  const _Float16* vb = vT + (size_t)(b * 1024 + hh * 64) * 512;

  // K fragments for tile 0 (prefetched each iteration thereafter)
  half8v ak[4];
#pragma unroll
  for (int kg = 0; kg < 4; kg++)
    ak[kg] = *(const half8v*)(kb + (size_t)l31 * 1024 + kg * 16 + hi * 8);

  for (int nt = 0; nt < 16; nt++) {
    // V^T fragments for this tile (used at the end -> latency hidden)
    half8v av[2][2];
#pragma unroll
    for (int dv = 0; dv < 2; dv++)
#pragma unroll
      for (int kc = 0; kc < 2; kc++)
        av[dv][kc] = *(const half8v*)(vb + (size_t)(dv * 32 + l31) * 512 + nt * 32 + kc * 16 + hi * 8);

    // S^T[kv][q] = sum_d K[kv][d] * Q[q][d]
    f32x16 st = {};
#pragma unroll
    for (int kg = 0; kg < 4; kg++)
      st = __builtin_amdgcn_mfma_f32_32x32x16_f16(ak[kg], bq[kg], st, 0, 0, 0);

    // prefetch next K tile
    if (nt < 15) {
#pragma unroll
      for (int kg = 0; kg < 4; kg++)
        ak[kg] = *(const half8v*)(kb + (size_t)((nt + 1) * 32 + l31) * 1024 + kg * 16 + hi * 8);
    }

    // z = raw*0.125*log2e + maskbias ; kv = (r&3) + 8*(r>>2) + 4*hi
    float sc[16];
#pragma unroll
    for (int j = 0; j < 4; j++) {
      const float4 mk = *(const float4*)&Msk[nt * 32 + j * 8 + hi * 4];
      sc[4 * j + 0] = fmaf(st[4 * j + 0], SC_L2E, mk.x);
      sc[4 * j + 1] = fmaf(st[4 * j + 1], SC_L2E, mk.y);
      sc[4 * j + 2] = fmaf(st[4 * j + 2], SC_L2E, mk.z);
      sc[4 * j + 3] = fmaf(st[4 * j + 3], SC_L2E, mk.w);
    }

    // row-max: local tree + one cross-half shuffle
    float tr[8];
#pragma unroll
    for (int r = 0; r < 8; r++) tr[r] = fmaxf(sc[r], sc[r + 8]);
#pragma unroll
    for (int r = 0; r < 4; r++) tr[r] = fmaxf(tr[r], tr[r + 4]);
    float tmax = fmaxf(fmaxf(tr[0], tr[1]), fmaxf(tr[2], tr[3]));
    tmax = fmaxf(tmax, __shfl_xor(tmax, 32, 64));

    const float mnew = fmaxf(m_s, tmax);
    const float mc = fmaxf(mnew, -1e30f);
    const float corr = EXP2(fmaxf(m_s, -1e30f) - mc);
    m_s = mnew;

    float p[16];
#pragma unroll
    for (int r = 0; r < 16; r++) p[r] = EXP2(sc[r] - mc);

    // pack P -> fp16 pairs: pk[j][pp] holds kv = 8j + 4hi + 2pp + {0,1}
    unsigned int pk[4][2];
#pragma unroll
    for (int j = 0; j < 4; j++)
#pragma unroll
      for (int pp = 0; pp < 2; pp++)
        pk[j][pp] = __builtin_bit_cast(
            unsigned int, CVTPK(p[4 * j + 2 * pp], p[4 * j + 2 * pp + 1]));

    // row-sum (tree, in place) + cross-half
    {
#pragma unroll
      for (int r = 0; r < 8; r++) p[r] += p[r + 8];
#pragma unroll
      for (int r = 0; r < 4; r++) p[r] += p[r + 4];
      float ts = (p[0] + p[1]) + (p[2] + p[3]);
      ts += __shfl_xor(ts, 32, 64);
      l_s = l_s * corr + ts;
    }

#pragma unroll
    for (int r = 0; r < 16; r++) { ot0[r] *= corr; ot1[r] *= corr; }

    // assemble PV B-frags: pb[kc] = P[q = l31][kv = kc*16 + hi*8 + 0..7]
    half8v pb[2];
#pragma unroll
    for (int kc = 0; kc < 2; kc++) {
      unsigned int w[4];
#pragma unroll
      for (int pp = 0; pp < 2; pp++) {
        const unsigned int x = pk[2 * kc][pp];      // j = 2kc   (for hi=0)
        const unsigned int y = pk[2 * kc + 1][pp];  // j = 2kc+1 (for hi=1)
        const unsigned int xp = __shfl_xor(x, 32, 64);
        const unsigned int yp = __shfl_xor(y, 32, 64);
        w[pp]     = hi ? yp : x;   // word from partner-half hi_src=0
        w[2 + pp] = hi ? y  : xp;  // word from partner-half hi_src=1
      }
      uint4 u; u.x = w[0]; u.y = w[1]; u.z = w[2]; u.w = w[3];
      pb[kc] = __builtin_bit_cast(half8v, u);
    }

    // O^T[d][q] += V^T[d][kv] * P[q][kv]
    ot0 = __builtin_amdgcn_mfma_f32_32x32x16_f16(av[0][0], pb[0], ot0, 0, 0, 0);
    ot0 = __builtin_amdgcn_mfma_f32_32x32x16_f16(av[0][1], pb[1], ot0, 0, 0, 0);
    ot1 = __builtin_amdgcn_mfma_f32_32x32x16_f16(av[1][0], pb[0], ot1, 0, 0, 0);
    ot1 = __builtin_amdgcn_mfma_f32_32x32x16_f16(av[1][1], pb[1], ot1, 0, 0, 0);
  }

  // normalize (all-masked rows -> l=0 -> zeros) and transpose via LDS
  const float inv = (l_s > 0.f) ? (1.f / l_s) : 0.f;
#pragma unroll
  for (int dv = 0; dv < 2; dv++) {
#pragma unroll
    for (int j = 0; j < 4; j++)
#pragma unroll
      for (int pp = 0; pp < 2; pp++) {
        const int r = 4 * j + 2 * pp;
        const float v0 = (dv ? ot1[r] : ot0[r]) * inv;
        const float v1 = (dv ? ot1[r + 1] : ot0[r + 1]) * inv;
        const int col = dv * 32 + 8 * j + 4 * hi + 2 * pp;  // d index
        const int pos = l31 * 64 + (col ^ (8 * (l31 & 7)));
        *(unsigned int*)&Ot[wid][pos] = __builtin_bit_cast(unsigned int, CVTPK(v0, v1));
      }
  }
  __syncthreads();
#pragma unroll
  for (int qh = 0; qh < 2; qh++)
#pragma unroll
    for (int k2 = 0; k2 < 2; k2++) {
      const int qq = qh * 16 + (lane >> 2);
      const int c  = (lane & 3) * 8 + k2 * 32;
      const half8v val = *(const half8v*)&Ot[wid][qq * 64 + (c ^ (8 * (qq & 7)))];
      *(half8v*)(ctx + (size_t)(tok0 + qq) * 1024 + hh * 64 + c) = val;
    }
}

// ---------------------------------------------------------------------------
extern "C" void kernel_launch(void* const* d_in, const int* in_sizes, int n_in,
                              void* d_out, int out_size, void* d_ws, size_t ws_size,
                              hipStream_t stream) {
  const float* text    = (const float*)d_in[0];
  const float* regions = (const float*)d_in[1];
  const void*  mask    = d_in[2];
  const float* Wq      = (const float*)d_in[3];
  const float* Wk      = (const float*)d_in[4];
  const float* Wv      = (const float*)d_in[5];
  const float* Wo      = (const float*)d_in[6];
  const float* bo      = (const float*)d_in[7];
  const float* gq      = (const float*)d_in[8];
  const float* bq      = (const float*)d_in[9];
  const float* gkv     = (const float*)d_in[10];
  const float* bkv     = (const float*)d_in[11];

  _Float16* ws16 = (_Float16*)d_ws;
  _Float16* wq16 = ws16;                  // 1M halves each
  _Float16* wk16 = wq16 + 1048576;
  _Float16* wv16 = wk16 + 1048576;
  _Float16* wo16 = wv16 + 1048576;
  _Float16* at16 = wo16 + 1048576;        // 16.7M halves (LN text / LN regions / raw regions)
  _Float16* q16  = at16 + 16777216;       // 16.7M (doubles as ctx)
  _Float16* k16  = q16 + 16777216;        // 4.2M
  _Float16* vTb  = k16 + 4194304;         // 4.2M  (V^T: [b*1024 + col][512])
  int* flag = (int*)(vTb + 4194304);

  detect_mask_kernel<<<1, 256, 0, stream>>>((const unsigned char*)mask, flag);

  cast_f2h_kernel<<<512, 256, 0, stream>>>(Wq, wq16, 131072);
  cast_f2h_kernel<<<512, 256, 0, stream>>>(Wk, wk16, 131072);
  cast_f2h_kernel<<<512, 256, 0, stream>>>(Wv, wv16, 131072);
  cast_f2h_kernel<<<512, 256, 0, stream>>>(Wo, wo16, 131072);

  // q = LN(text) @ Wq^T
  ln_cast_kernel<<<16384, 256, 0, stream>>>(text, gq, bq, at16);
  hgemm_nt<0><<<dim3(128, 8), 256, 0, stream>>>(at16, wq16, q16, nullptr, nullptr);

  // k = LN(regions) @ Wk^T
  ln_cast_kernel<<<4096, 256, 0, stream>>>(regions, gkv, bkv, at16);
  hgemm_nt<0><<<dim3(32, 8), 256, 0, stream>>>(at16, wk16, k16, nullptr, nullptr);

  // vT = (regions @ Wv^T)^T   (transposed epilogue write)
  cast_f2h_kernel<<<2048, 256, 0, stream>>>(regions, at16 + 4194304, 524288);
  hgemm_nt<2><<<dim3(32, 8), 256, 0, stream>>>(at16 + 4194304, wv16, vTb, nullptr, nullptr);

  // attention (ctx overwrites q16; block-private rows/cols)
  attn_v3<<<2048, 256, 0, stream>>>(q16, k16, vTb, mask, flag, q16);

  // out = text + ctx @ Wo^T + bo
  hgemm_nt<1><<<dim3(128, 8), 256, 0, stream>>>(q16, wo16, d_out, bo, text);
}